// Round 16
// baseline (322.193 us; speedup 1.0000x reference)
//
#include <hip/hip_runtime.h>

// ============================================================================
// LeViT attention, MI355X. v25 = v24 (fused xtw|qkv|attn + separate proj;
// spin-barrier + sc1 cross-phase stores -- produced CORRECT output on v24's
// verification run, absmax 0.002197266) with the replay hazard fixed:
//  - barrier counter moved from out[0] (stale on graph replay -> barriers
//    no-op'd -> race on re-run) into ws at R+3,000,000 u16: above xpk's
//    span [0, 1,605,632) so phases 1-2 never touch it; phase-3 opk clobbers
//    it only AFTER the last barrier; proj reads that cell as real attn data.
//  - hipMemsetAsync(ctr, 0, 8, stream) at the top of kernel_launch
//    (graph-captured, replays every iteration; harness itself uses
//    hipMemsetAsync under capture).
// Structure: normal <<<512,256>>> launch, lb(256,2) -> 2 blocks/CU -> all
// 512 blocks co-resident (no deadlock); device-scope spin barrier; sc1
// (agent) write-through stores for all phase-1/2 cross-phase data; opk/xpk
// alias published to proj by the kernel boundary (v17-proven).
// Phase bodies byte-identical to proven v17/v20 kernels.
// ws (u16): qws 802816 | kws 802816 | vpk 3211264 | R 3211264 (xpk/opk;
//   ctr at R+3,000,000) | wqpk 32768 | wkpk 32768 | wvpk 131072 |
//   wppk 131072 => 16,711,680 B
// MFMA 16x16x32_bf16: A[m=l15][k=quad*8+j]; B[k=quad*8+j][n=l15];
// C/D: col=l15, row=quad*4+reg.
// vpk layout (proven v13): vpk[((bh*49+c)*8 + (c32*4+dt))*512 + lane*8 + j]
//   = V[bh][d=dt*16+(lane&15)][key=c*64+c32*32+(j>>2)*16+(lane>>4)*4+(j&3)]
// ============================================================================

typedef short  s16x8 __attribute__((ext_vector_type(8)));
typedef float  f32x4 __attribute__((ext_vector_type(4)));
typedef int    i32x4 __attribute__((ext_vector_type(4)));
typedef unsigned short u16;
typedef unsigned short u16x4 __attribute__((ext_vector_type(4)));
typedef unsigned long long u64;

#define NB 512   // grid blocks; lb(256,2) guarantees all co-resident

__device__ __forceinline__ u16 f2bf(float f) {   // RNE
    unsigned u = __builtin_bit_cast(unsigned, f);
    u += 0x7FFF + ((u >> 16) & 1);
    return (u16)(u >> 16);
}
__device__ __forceinline__ f32x4 mfma32(s16x8 a, s16x8 b, f32x4 c) {
    return __builtin_amdgcn_mfma_f32_16x16x32_bf16(a, b, c, 0, 0, 0);
}
__device__ __forceinline__ int cvtpk(float lo, float hi) { // 2xf32 -> 2xbf16
    int r;
    asm("v_cvt_pk_bf16_f32 %0, %1, %2" : "=v"(r) : "v"(lo), "v"(hi));
    return r;
}
// Agent-scope write-through stores (sc1): visible at the coherence point (IC)
// across XCDs; the fence before the barrier waits the acks.
__device__ __forceinline__ void st16_wt(u16* p, s16x8 v) {
    u64 q0 = *(const u64*)&v;
    u64 q1 = ((const u64*)&v)[1];
    __hip_atomic_store((u64*)p,     q0, __ATOMIC_RELAXED, __HIP_MEMORY_SCOPE_AGENT);
    __hip_atomic_store((u64*)p + 1, q1, __ATOMIC_RELAXED, __HIP_MEMORY_SCOPE_AGENT);
}
__device__ __forceinline__ void st2_wt(u16* p, u16 v) {
    __hip_atomic_store(p, v, __ATOMIC_RELAXED, __HIP_MEMORY_SCOPE_AGENT);
}
// Grid barrier: all NB blocks arrive; spin until target. Counter zeroed by
// the captured hipMemsetAsync before every launch. Monotonic targets.
__device__ __forceinline__ void gbar(unsigned* ctr, unsigned target) {
    __syncthreads();
    __threadfence();                              // publish prior stores
    if (threadIdx.x == 0) {
        __hip_atomic_fetch_add(ctr, 1u, __ATOMIC_ACQ_REL, __HIP_MEMORY_SCOPE_AGENT);
        while (__hip_atomic_load(ctr, __ATOMIC_ACQUIRE, __HIP_MEMORY_SCOPE_AGENT) < target)
            __builtin_amdgcn_s_sleep(2);
    }
    __syncthreads();
}

__global__ __launch_bounds__(256, 2) void fused_kernel(
    const float* __restrict__ x,
    const float* __restrict__ wq, const float* __restrict__ sq,
    const float* __restrict__ wk, const float* __restrict__ sk,
    const float* __restrict__ wv, const float* __restrict__ sv,
    const float* __restrict__ wp, const float* __restrict__ sp,
    const float* __restrict__ bq, const float* __restrict__ bk,
    const float* __restrict__ bv,
    unsigned* __restrict__ ctr,
    u16* __restrict__ qws, u16* __restrict__ kws, u16* __restrict__ vpk,
    u16* __restrict__ xpk, u16* __restrict__ opk,
    u16* __restrict__ wqpk, u16* __restrict__ wkpk,
    u16* __restrict__ wvpk, u16* __restrict__ wppk)
{
    const int blk = blockIdx.x;
    const int t   = threadIdx.x;
    __shared__ float lds[32][65];

    // ================= Phase 1: weight pack (items 0..195) + x transpose
    // (items 196..979; 64n x 32c tiles, proven v20 body; sc1 stores) =======
    for (int it = blk; it < 980; it += NB) {
        if (it < 196) {
            int ch = it * 256 + t;
            const float *W, *S; u16* dst; int nkc; bool ok = true;
            if (ch < 4096)        { W = wq; S = sq; dst = wqpk; nkc = 8; }
            else if (ch < 8192)   { W = wk; S = sk; dst = wkpk; nkc = 8;  ch -= 4096; }
            else if (ch < 24576)  { W = wv; S = sv; dst = wvpk; nkc = 8;  ch -= 8192; }
            else if (ch < 40960)  { W = wp; S = sp; dst = wppk; nkc = 16; ch -= 24576; }
            else ok = false;
            if (ok) {
                const int lane = ch & 63, kc = (ch >> 6) % nkc, rt = (ch >> 6) / nkc;
                const int l15 = lane & 15, q = lane >> 4;
                const int row = rt * 16 + l15, C = nkc * 32;
                const float sc = S[row];
                const float* src = &W[row * C + kc * 32 + q * 8];
                s16x8 o;
                #pragma unroll
                for (int j = 0; j < 8; j++) o[j] = (short)f2bf(src[j] * sc);
                st16_wt(&dst[ch * 8], o);
            }
        } else {
            const int j  = it - 196;
            const int b  = j / 392, r = j % 392;
            const int kg = r / 49, c0 = kg * 32, n0 = (r % 49) * 64;
            const int nl = t & 63, cl = t >> 6;
            #pragma unroll
            for (int i = 0; i < 8; i++) {
                const int c = cl + i * 4;        // 0..31
                lds[c][nl] = x[(b * 256 + c0 + c) * 3136 + n0 + nl];
            }
            __syncthreads();
            {
                const int t16l = t >> 6, lane = t & 63;
                const int l15 = lane & 15, q = lane >> 4;
                s16x8 o;
                #pragma unroll
                for (int jj = 0; jj < 8; jj++)
                    o[jj] = (short)f2bf(lds[q * 8 + jj][t16l * 16 + l15]);
                const int tg = (n0 >> 4) + t16l;
                st16_wt(&xpk[(((b * 196 + tg) * 8 + kg) * 64 + lane) * 8], o);
            }
            __syncthreads();                     // lds reused next iteration
        }
    }
    gbar(ctr, NB);                               // phase 1 -> 2

    // ================= Phase 2: qkv (items 1176 = 98 x 6 x 2, v20 body;
    // sc1 stores to qws/kws/vpk) ============================================
    for (int it = blk; it < 1176; it += NB) {
        const int bx = it % 98, rt = (it / 98) % 6, b = it / 588;
        const int wave = t >> 6, lane = t & 63;
        const int l15 = lane & 15, quad = lane >> 4;
        const f32x4 z = {0.f, 0.f, 0.f, 0.f};

        if (rt < 2) {
            const float qs = 1.44269504088896f;  // fold log2e into q
            const int wl = wave & 1, fh = wave >> 1;
            const int m_t = bx * 2 + wl;         // token-tile 0..195
            const int m0  = m_t * 16;
            s16x8 a8[8];
            #pragma unroll
            for (int kc8 = 0; kc8 < 8; kc8++)
                a8[kc8] = *(const s16x8*)&xpk[(((b * 196 + m_t) * 8 + kc8) * 64 + lane) * 8];
            f32x4 aq_[2] = {z, z}, ak_[2] = {z, z};
            #pragma unroll
            for (int kc8 = 0; kc8 < 8; kc8++) {
                #pragma unroll
                for (int ff = 0; ff < 2; ff++) {
                    const int f = fh * 2 + ff;
                    const int wi = (((rt * 4 + f) * 8 + kc8) * 64 + lane) * 8;
                    s16x8 bfq = *(const s16x8*)&wqpk[wi];
                    aq_[ff] = mfma32(a8[kc8], bfq, aq_[ff]);
                    s16x8 bfk = *(const s16x8*)&wkpk[wi];
                    ak_[ff] = mfma32(a8[kc8], bfk, ak_[ff]);
                }
            }
            #pragma unroll
            for (int ff = 0; ff < 2; ff++) {
                const int f   = fh * 2 + ff;
                const int och = rt * 64 + f * 16 + l15;
                const float biq = bq[och], bik = bk[och];
                const int h = och >> 4;
                #pragma unroll
                for (int r = 0; r < 4; r++) {
                    const int tok = m0 + quad * 4 + r;
                    st2_wt(&qws[((b * 8 + h) * 3136 + tok) * 16 + l15],
                           f2bf((aq_[ff][r] + biq) * qs));
                    st2_wt(&kws[((b * 8 + h) * 3136 + tok) * 16 + l15],
                           f2bf(ak_[ff][r] + bik));
                }
            }
        } else {
            const int h0 = (rt - 2) * 2, h1 = h0 + 1;
            const int c = bx >> 1, half = bx & 1;
            s16x8 a80[8], a81[8];
            #pragma unroll
            for (int kc8 = 0; kc8 < 8; kc8++) {
                a80[kc8] = *(const s16x8*)&wvpk[(((h0 * 4 + wave) * 8 + kc8) * 64 + lane) * 8];
                a81[kc8] = *(const s16x8*)&wvpk[(((h1 * 4 + wave) * 8 + kc8) * 64 + lane) * 8];
            }
            f32x4 ac0[2] = {z, z}, ac1[2] = {z, z};
            #pragma unroll
            for (int kc8 = 0; kc8 < 8; kc8++) {
                #pragma unroll
                for (int ff = 0; ff < 2; ff++) {
                    const int f = half * 2 + ff;
                    s16x8 bf = *(const s16x8*)&xpk[(((b * 196 + c * 4 + f) * 8 + kc8) * 64 + lane) * 8];
                    ac0[ff] = mfma32(a80[kc8], bf, ac0[ff]);
                    ac1[ff] = mfma32(a81[kc8], bf, ac1[ff]);
                }
            }
            // Packed V write (proven v13 layout), sc1 stores
            #pragma unroll
            for (int hh = 0; hh < 2; hh++) {
                const int h = hh ? h1 : h0;
                const f32x4* ac = hh ? ac1 : ac0;
                const int och0v = h * 64 + wave * 16;
                u16* vdst = &vpk[(((b * 8 + h) * 49 + c) * 8) * 512];
                #pragma unroll
                for (int r = 0; r < 4; r++) {
                    const float bi = bv[och0v + quad * 4 + r];
                    const int lane_r8 = ((l15 >> 2) * 16 + quad * 4 + r) * 8;
                    #pragma unroll
                    for (int ff = 0; ff < 2; ff++) {
                        const int idx = (half * 4 + wave) * 512 + lane_r8 + ff * 4 + (l15 & 3);
                        st2_wt(&vdst[idx], f2bf(ac[ff][r] + bi));
                    }
                }
            }
        }
    }
    gbar(ctr, 2 * NB);                           // phase 2 -> 3 (last ctr use)

    // ================= Phase 3: attn (v17 body, per-wave items) ============
    // XCD class = blk%8 serves bh in {cls, cls+8} (v17's proven L2 pattern).
    // 512 blocks x 4 waves = 2048 slots; 196 items per cls (il < 196).
    {
        const int wave = t >> 6, lane = t & 63;
        const int cls = blk & 7;
        const int il  = (blk >> 3) * 4 + wave;   // 0..255 per cls
        if (il < 196) {
            const int bh = cls + 8 * (il & 1);
            const int yq = il >> 1;
            const int nb = yq * 32;
            const int l15 = lane & 15, quad = lane >> 4;

            s16x8 aq[2];
            #pragma unroll
            for (int u = 0; u < 2; u++) {
                aq[u] = (s16x8){0, 0, 0, 0, 0, 0, 0, 0};
                if (quad < 2)
                    aq[u] = *(const s16x8*)&qws[(bh * 3136 + nb + u * 16 + l15) * 16 + quad * 8];
            }
            s16x8 ones;
            #pragma unroll
            for (int i = 0; i < 8; i++) ones[i] = (short)0x3F80;   // bf16 1.0

            const u16* krow = &kws[(bh * 3136 + l15) * 16 + (quad & 1) * 8];
            const u16* vb   = &vpk[bh * 49 * 4096 + lane * 8];

            f32x4 acc[2][4], acc5[2];
            #pragma unroll
            for (int u = 0; u < 2; u++) {
                #pragma unroll
                for (int dt = 0; dt < 4; dt++) acc[u][dt] = (f32x4){0.f, 0.f, 0.f, 0.f};
                acc5[u] = (f32x4){0.f, 0.f, 0.f, 0.f};
            }
            const f32x4 z = {0.f, 0.f, 0.f, 0.f};

            s16x8 kfA[4], vfA[8], kfB[4], vfB[8];
            auto loadK = [&](s16x8* kf, int c) {
                #pragma unroll
                for (int ii = 0; ii < 4; ii++)
                    kf[ii] = *(const s16x8*)&krow[(c * 64 + ii * 16) * 16];
            };
            auto loadV = [&](s16x8* vf, int c) {
                #pragma unroll
                for (int i = 0; i < 8; i++)
                    vf[i] = *(const s16x8*)&vb[(c * 8 + i) * 512];
            };
            auto compute = [&](const s16x8* kf, const s16x8* vf) {
                #pragma unroll
                for (int u = 0; u < 2; u++) {
                    f32x4 s[4];
                    #pragma unroll
                    for (int ii = 0; ii < 4; ii++) s[ii] = mfma32(kf[ii], aq[u], z);
                    float e[4][4];
                    #pragma unroll
                    for (int ii = 0; ii < 4; ii++)
                        #pragma unroll
                        for (int r = 0; r < 4; r++)
                            e[ii][r] = __builtin_amdgcn_exp2f(s[ii][r]);
                    s16x8 pf[2];
                    #pragma unroll
                    for (int c32 = 0; c32 < 2; c32++) {
                        i32x4 pk;
                        pk[0] = cvtpk(e[2 * c32][0],     e[2 * c32][1]);
                        pk[1] = cvtpk(e[2 * c32][2],     e[2 * c32][3]);
                        pk[2] = cvtpk(e[2 * c32 + 1][0], e[2 * c32 + 1][1]);
                        pk[3] = cvtpk(e[2 * c32 + 1][2], e[2 * c32 + 1][3]);
                        pf[c32] = __builtin_bit_cast(s16x8, pk);
                    }
                    __builtin_amdgcn_s_setprio(1);
                    #pragma unroll
                    for (int c32 = 0; c32 < 2; c32++) {
                        #pragma unroll
                        for (int dt = 0; dt < 4; dt++)
                            acc[u][dt] = mfma32(vf[c32 * 4 + dt], pf[c32], acc[u][dt]);
                        acc5[u] = mfma32(ones, pf[c32], acc5[u]);
                    }
                    __builtin_amdgcn_s_setprio(0);
                }
            };

            loadK(kfA, 0); loadV(vfA, 0);
            #pragma unroll 1
            for (int c = 0; c < 49; c += 2) {
                if (c + 1 < 49) { loadK(kfB, c + 1); loadV(vfB, c + 1); }
                compute(kfA, vfA);
                if (c + 2 < 49) { loadK(kfA, c + 2); loadV(vfA, c + 2); }
                if (c + 1 < 49) compute(kfB, vfB);
            }

            const int bq_ = bh >> 3, h = bh & 7;
            #pragma unroll
            for (int u = 0; u < 2; u++) {
                const float inv = 1.0f / acc5[u][0];
                const int tt = yq * 2 + u;
                u16* ob = &opk[((bq_ * 196 + tt) * 16) * 512];
                #pragma unroll
                for (int dt = 0; dt < 4; dt++) {
                    u16x4 o4;
                    #pragma unroll
                    for (int r = 0; r < 4; r++) o4[r] = f2bf(acc[u][dt][r] * inv);
                    *(u16x4*)&ob[(h * 2 + (dt >> 1)) * 512 +
                                 (((dt & 1) * 2 + (quad >> 1)) * 16 + l15) * 8 +
                                 (quad & 1) * 4] = o4;
                }
            }
        }
    }
    // kernel ends; the kernel boundary (proven by v17) publishes opk for proj.
}

// ---------------------------------------------------------------------------
// Output projection (separate kernel, proven v20 body): 16-token blocks.
// grid (196,4,2), 256 thr. A = wppk packed, B = opk; C[och][token] -> fp32.
// ---------------------------------------------------------------------------
__global__ __launch_bounds__(256, 4) void proj_kernel(
    const u16* __restrict__ opk, const u16* __restrict__ wppk,
    const float* __restrict__ bp, float* __restrict__ out)
{
    const int b = blockIdx.z, n0 = blockIdx.x * 16;
    const int och0 = blockIdx.y * 64 + (threadIdx.x >> 6) * 16;
    const int lane = threadIdx.x & 63;
    const int l15 = lane & 15, quad = lane >> 4;
    const f32x4 z = {0.f, 0.f, 0.f, 0.f};

    const int och_t = blockIdx.y * 4 + (threadIdx.x >> 6);
    s16x8 a8[16];
    #pragma unroll
    for (int kc = 0; kc < 16; kc++)
        a8[kc] = *(const s16x8*)&wppk[((och_t * 16 + kc) * 64 + lane) * 8];
    f32x4 acc = z;
    #pragma unroll
    for (int kc = 0; kc < 16; kc++) {
        s16x8 bf = *(const s16x8*)&opk[(((b * 196 + blockIdx.x) * 16 + kc) * 64 + lane) * 8];
        acc = mfma32(a8[kc], bf, acc);
    }
    #pragma unroll
    for (int r = 0; r < 4; r++) {
        const int och = och0 + quad * 4 + r;
        out[(b * 256 + och) * 3136 + n0 + l15] = acc[r] + bp[och];
    }
}

// ---------------------------------------------------------------------------
extern "C" void kernel_launch(void* const* d_in, const int* in_sizes, int n_in,
                              void* d_out, int out_size, void* d_ws, size_t ws_size,
                              hipStream_t stream) {
    const float* x  = (const float*)d_in[0];
    const float* wq = (const float*)d_in[1];
    const float* sq = (const float*)d_in[2];
    const float* bq = (const float*)d_in[3];
    const float* wk = (const float*)d_in[4];
    const float* sk = (const float*)d_in[5];
    const float* bk = (const float*)d_in[6];
    const float* wv = (const float*)d_in[7];
    const float* sv = (const float*)d_in[8];
    const float* bv = (const float*)d_in[9];
    const float* wp = (const float*)d_in[10];
    const float* sp = (const float*)d_in[11];
    const float* bp = (const float*)d_in[12];
    float* out = (float*)d_out;

    u16* qws  = (u16*)d_ws;                // 802816
    u16* kws  = qws + 802816;              // 802816
    u16* vpk  = kws + 802816;              // 3211264 (packed V)
    u16* R    = vpk + 3211264;             // 3211264 (xpk phases 1-2, opk after)
    u16* xpk  = R;
    u16* opk  = R;
    u16* wqpk = R + 3211264;               // 32768
    u16* wkpk = wqpk + 32768;              // 32768
    u16* wvpk = wkpk + 32768;              // 131072
    u16* wppk = wvpk + 131072;             // 131072  (total 16,711,680 B)

    // Barrier counter: upper half of R (above xpk's 1,605,632-u16 span).
    // Phases 1-2 never touch it; phase-3 opk clobbers it only after the
    // last barrier; the captured memset re-zeros it every launch/replay.
    unsigned* ctr = (unsigned*)(R + 3000000);
    hipMemsetAsync(ctr, 0, 8, stream);

    fused_kernel<<<dim3(NB), dim3(256), 0, stream>>>(
        x, wq, sq, wk, sk, wv, sv, wp, sp, bq, bk, bv,
        ctr, qws, kws, vpk, xpk, opk, wqpk, wkpk, wvpk, wppk);
    proj_kernel<<<dim3(196, 4, 2), 256, 0, stream>>>(opk, wppk, bp, out);
}